// Round 13
// baseline (251.202 us; speedup 1.0000x reference)
//
#include <hip/hip_runtime.h>

// ---- problem constants (from reference) ----
#define SEQ      10688      // IMG_LEN + TEXT_LEN
#define IMG_LEN  10368      // 18*24*24
#define TEXT_LEN 320
#define DH       128
#define NHEADS   4
#define SLAB     3456       // 6*24*24 tokens per time-slab
#define KVC      32         // kv chunk rows
#define QT       128        // q rows per block (4 waves x 32)
#define NIT      81         // image q-tiles per head
#define NTT      3          // text q-tiles per head (last tile half-valid)
#define NCH_TXT  334        // SEQ/KVC
#define NCH_IMG  118        // 108 slab chunks + 10 text chunks
#define SCALEL2E 0.12751744518924593f   // (1/sqrt(128)) * log2(e)
#define DEFER_THR 8.0f      // defer-max rescale threshold (T13)

typedef __bf16 bf16x8 __attribute__((ext_vector_type(8)));
typedef __bf16 bf16x4 __attribute__((ext_vector_type(4)));
typedef float  f32x4  __attribute__((ext_vector_type(4)));

__device__ __forceinline__ unsigned pk2bf(float a, float b) {
    union { __bf16 h[2]; unsigned u; } t;
    t.h[0] = (__bf16)a; t.h[1] = (__bf16)b;
    return t.u;
}

__device__ __forceinline__ void gload_lds16(const void* g, void* l) {
    __builtin_amdgcn_global_load_lds(
        (const __attribute__((address_space(1))) void*)g,
        (__attribute__((address_space(3))) void*)l, 16, 0, 0);
}

__device__ __forceinline__ void split_range(int total, int nsplit, int s, int& c0, int& n) {
    const int q = total / nsplit, r = total % nsplit;
    if (s < r) { c0 = s * (q + 1); n = q + 1; }
    else       { c0 = r * (q + 1) + (s - r) * q; n = q; }
}

template<int TS, int IS> struct Geo {
    static constexpr int NTXTB = NHEADS * NTT * TS;
    static constexpr int NIMGB = NHEADS * NIT * IS;
    static constexpr int NPID  = NTXTB + NIMGB;
    static constexpr size_t WS_FLOATS = (size_t)NPID * (QT * DH + QT * 2);
};
#define KB_BYTES ((size_t)NHEADS * SEQ * DH * 2)   // bf16 K (or V^T) array size

// ---- pre-pass: K -> bf16 (same layout); V -> bf16 TRANSPOSED [head][d][kv] ----
__global__ __launch_bounds__(256) void sta_prep(const float* __restrict__ Kg,
                                                const float* __restrict__ Vg,
                                                unsigned short* __restrict__ Kb,
                                                unsigned short* __restrict__ VTb) {
    __shared__ float T[64][65];
    const int b = blockIdx.x;
    if (b < 2672) {                      // K convert: 4*SEQ*128 elems, 8/thread
        const size_t i = ((size_t)b * 256 + threadIdx.x) * 8;
        float4 a = *(const float4*)(Kg + i);
        float4 c = *(const float4*)(Kg + i + 4);
        uint4 u; u.x = pk2bf(a.x, a.y); u.y = pk2bf(a.z, a.w);
                 u.z = pk2bf(c.x, c.y); u.w = pk2bf(c.z, c.w);
        *(uint4*)(Kb + i) = u;
    } else {                             // V transpose: 64kv x 64d LDS tile
        const int bb = b - 2672;
        const int dt = bb & 1, kvt = (bb >> 1) % 167, h = (bb >> 1) / 167;
        const float* src = Vg + ((size_t)h * SEQ + kvt * 64) * DH + dt * 64;
        const int t = threadIdx.x;
        const int col = t & 63, r4 = t >> 6;
        #pragma unroll
        for (int i = 0; i < 16; ++i) {
            const int row = i * 4 + r4;
            T[row][col] = src[(size_t)row * DH + col];
        }
        __syncthreads();
        unsigned short* dst = VTb + ((size_t)h * DH + dt * 64) * SEQ + kvt * 64;
        const int kp = t & 31, dq = t >> 5;
        #pragma unroll
        for (int i = 0; i < 8; ++i) {
            const int dd = i * 8 + dq;
            unsigned u = pk2bf(T[kp * 2][dd], T[kp * 2 + 1][dd]);
            *(unsigned*)(dst + (size_t)dd * SEQ + kp * 2) = u;
        }
    }
}

// K fragments read DIRECTLY from global bf16 Kb (no LDS): the 4 waves of a
// block read the same 8KB tile -> L1-hit after first wave. Moves K traffic
// off the saturated LDS pipe (measured 85 B/cy/CU = the R12 bottleneck) onto
// the parallel TA/L1 path. V stays LDS (DMA + swizzle + dbuf, 1 barrier/chunk).
// NOTE: NO min-waves clamp (rounds 3/5 spill catastrophe).
template<int TS, int IS, bool SPLIT>
__global__ __launch_bounds__(256) void sta_attn(const float* __restrict__ Qg,
                                                const unsigned short* __restrict__ Kb,
                                                const unsigned short* __restrict__ VTb,
                                                float* __restrict__ Og,
                                                float* __restrict__ Opart,
                                                float* __restrict__ Ml) {
    using G = Geo<TS, IS>;
    // V^T: [d][kv] bf16 (128x32), 16B-granule XOR key ((d>>1)&3).
    __shared__ __align__(16) unsigned short VT[2][DH * KVC];   // 16 KB total

    const int tid  = threadIdx.x;
    const int lane = tid & 63;
    const int wv   = tid >> 6;
    const int q    = lane & 15;       // MFMA col position (q for QK/PV outputs)
    const int g    = lane >> 4;       // lane group 0..3
    const int vkey = (q >> 1) & 3;    // V-read swizzle key (granule)
    const int gh   = g >> 1;
    const int gb   = (g & 1) * 8;     // byte sub-offset within V granule
    const int krow0 = q * 256 + g * 16;        // K global fragment offsets (bytes)
    const int krow1 = krow0 + 16 * 256;

    // per-lane V DMA source offsets (bytes), inverse-swizzled (chunk-invariant)
    int voff[2];
    #pragma unroll
    for (int j = 0; j < 2; ++j) {
        const int idx = wv * 128 + j * 64 + lane;            // linear 16B granule
        voff[j] = (idx >> 2) * (SEQ * 2) + (((idx & 3) ^ ((idx >> 3) & 3)) << 4);
    }

    int b = blockIdx.x;
    int head, qbase, nch, ch0, kvb0, pid = 0;
    bool isText;
    if (b < G::NTXTB) {                        // text splits first (longest poles)
        int tb = b / TS, s = b % TS;
        head = tb / NTT; qbase = IMG_LEN + (tb % NTT) * QT;
        isText = true; kvb0 = 0;
        split_range(NCH_TXT, TS, s, ch0, nch);
        pid = b;
    } else {
        int bb = b - G::NTXTB; int tile = bb / IS, s = bb % IS;
        head = tile / NIT; qbase = (tile % NIT) * QT;
        isText = false; kvb0 = (qbase / SLAB) * SLAB;
        split_range(NCH_IMG, IS, s, ch0, nch);
        pid = G::NTXTB + bb;
    }

    const size_t hoff = (size_t)head * SEQ * DH;
    const float* Qh = Qg + hoff;
    const char* khb = (const char*)Kb  + hoff * 2;            // kv-row stride 256B
    const char* vhb = (const char*)VTb + hoff * 2;            // d-row stride SEQ*2

    // ---- Q fragments for 2 q-subtiles (B-operand layout), scale folded ----
    bf16x8 qf[2][4];
    #pragma unroll
    for (int n = 0; n < 2; ++n) {
        int qr = qbase + wv * 32 + n * 16 + q;
        if (qr > SEQ - 1) qr = SEQ - 1;        // text tail: clamp (discarded at store)
        const float* qp = Qh + (size_t)qr * DH;
        #pragma unroll
        for (int c = 0; c < 4; ++c) {
            float4 a = *(const float4*)(qp + c * 32 + g * 8);
            float4 d = *(const float4*)(qp + c * 32 + g * 8 + 4);
            union { unsigned u[4]; bf16x8 v; } t;
            t.u[0] = pk2bf(a.x * SCALEL2E, a.y * SCALEL2E);
            t.u[1] = pk2bf(a.z * SCALEL2E, a.w * SCALEL2E);
            t.u[2] = pk2bf(d.x * SCALEL2E, d.y * SCALEL2E);
            t.u[3] = pk2bf(d.z * SCALEL2E, d.w * SCALEL2E);
            qf[n][c] = t.v;
        }
    }

    f32x4 o[2][8];
    #pragma unroll
    for (int n = 0; n < 2; ++n)
        #pragma unroll
        for (int dt = 0; dt < 8; ++dt) o[n][dt] = f32x4{0.f, 0.f, 0.f, 0.f};
    float mrun[2] = {-INFINITY, -INFINITY};
    float lsum[2] = {0.f, 0.f};

    auto kvaddr = [&](int gch) -> int {
        return isText ? gch * KVC
                      : (gch < 108 ? kvb0 + gch * KVC : IMG_LEN + (gch - 108) * KVC);
    };

    #define STAGE_V(BUF, KB)                                                     \
        {   const char* vs = vhb + (size_t)(KB) * 2;                             \
            gload_lds16(vs + voff[0], &VT[BUF][wv * 1024]);                      \
            gload_lds16(vs + voff[1], &VT[BUF][wv * 1024 + 512]);                \
        }

    STAGE_V(0, kvaddr(ch0));
    __syncthreads();                       // drains DMA (vmcnt) + syncs

    for (int ch = 0; ch < nch; ++ch) {
        const int buf = ch & 1;
        if (ch + 1 < nch) STAGE_V(buf ^ 1, kvaddr(ch0 + ch + 1));

        // ---- S^T = K * Q^T, K straight from global (L1-shared across waves) ----
        const char* kbase = khb + (size_t)kvaddr(ch0 + ch) * 256;
        f32x4 st[2][2];
        #pragma unroll
        for (int n = 0; n < 2; ++n)
            #pragma unroll
            for (int kt = 0; kt < 2; ++kt) st[n][kt] = f32x4{0.f, 0.f, 0.f, 0.f};
        __builtin_amdgcn_s_setprio(1);
        #pragma unroll
        for (int c = 0; c < 4; ++c) {
            bf16x8 kf0 = *(const bf16x8*)(kbase + krow0 + c * 64);
            bf16x8 kf1 = *(const bf16x8*)(kbase + krow1 + c * 64);
            st[0][0] = __builtin_amdgcn_mfma_f32_16x16x32_bf16(kf0, qf[0][c], st[0][0], 0, 0, 0);
            st[1][0] = __builtin_amdgcn_mfma_f32_16x16x32_bf16(kf0, qf[1][c], st[1][0], 0, 0, 0);
            st[0][1] = __builtin_amdgcn_mfma_f32_16x16x32_bf16(kf1, qf[0][c], st[0][1], 0, 0, 0);
            st[1][1] = __builtin_amdgcn_mfma_f32_16x16x32_bf16(kf1, qf[1][c], st[1][1], 0, 0, 0);
        }
        __builtin_amdgcn_s_setprio(0);

        // ---- online softmax (log2 domain), defer-max ----
        float cm[2];
        #pragma unroll
        for (int n = 0; n < 2; ++n) {
            float a0 = fmaxf(fmaxf(st[n][0][0], st[n][0][1]), fmaxf(st[n][0][2], st[n][0][3]));
            float a1 = fmaxf(fmaxf(st[n][1][0], st[n][1][1]), fmaxf(st[n][1][2], st[n][1][3]));
            float c0 = fmaxf(a0, a1);
            c0 = fmaxf(c0, __shfl_xor(c0, 16));
            c0 = fmaxf(c0, __shfl_xor(c0, 32));
            cm[n] = c0;
        }
        if (!__all((cm[0] <= mrun[0] + DEFER_THR) && (cm[1] <= mrun[1] + DEFER_THR))) {
            #pragma unroll
            for (int n = 0; n < 2; ++n) {
                float mnew = fmaxf(mrun[n], cm[n]);
                float sc = exp2f(mrun[n] - mnew);
                lsum[n] *= sc;
                #pragma unroll
                for (int dt = 0; dt < 8; ++dt) o[n][dt] *= sc;
                mrun[n] = mnew;
            }
        }

        // P in bf16: the K=16 B-fragment (k=g*4+j, col=q) IS the st layout ->
        // feeds PV directly, no LDS/shuffle redistribution.
        bf16x4 pkv[2][2];
        #pragma unroll
        for (int n = 0; n < 2; ++n) {
            float ps = 0.f;
            #pragma unroll
            for (int kt = 0; kt < 2; ++kt) {
                float p0 = exp2f(st[n][kt][0] - mrun[n]);
                float p1 = exp2f(st[n][kt][1] - mrun[n]);
                float p2 = exp2f(st[n][kt][2] - mrun[n]);
                float p3 = exp2f(st[n][kt][3] - mrun[n]);
                ps += (p0 + p1) + (p2 + p3);
                union { unsigned u[2]; bf16x4 v; } t;
                t.u[0] = pk2bf(p0, p1);
                t.u[1] = pk2bf(p2, p3);
                pkv[n][kt] = t.v;
            }
            ps += __shfl_xor(ps, 16);
            ps += __shfl_xor(ps, 32);
            lsum[n] += ps;
        }

        // ---- O^T += V^T * P^T via K=16 MFMA, A=V^T from LDS (b64), B=pkv regs ----
        __builtin_amdgcn_s_setprio(1);
        #pragma unroll
        for (int kt = 0; kt < 2; ++kt) {
            bf16x4 vfr[8];
            #pragma unroll
            for (int dt = 0; dt < 8; ++dt) {
                const int d = dt * 16 + q;
                vfr[dt] = *(const bf16x4*)((const char*)&VT[buf][0]
                            + d * 64 + (((kt * 2 + gh) ^ vkey) << 4) + gb);
            }
            #pragma unroll
            for (int dt = 0; dt < 8; ++dt) {
                asm("v_mfma_f32_16x16x16_bf16 %0, %1, %2, %0"
                    : "+v"(o[0][dt]) : "v"(vfr[dt]), "v"(pkv[0][kt]));
                asm("v_mfma_f32_16x16x16_bf16 %0, %1, %2, %0"
                    : "+v"(o[1][dt]) : "v"(vfr[dt]), "v"(pkv[1][kt]));
            }
        }
        __builtin_amdgcn_s_setprio(0);

        if (ch + 1 < nch) __syncthreads();     // drains V DMA + syncs readers
    }

    // hazard insurance: asm MFMA writes o[], epilogue VALU reads it soon after
    asm volatile("s_nop 7\n\ts_nop 7");

    if constexpr (SPLIT) {
        float* opb = Opart + (size_t)pid * (QT * DH);
        #pragma unroll
        for (int n = 0; n < 2; ++n) {
            const int row = wv * 32 + n * 16 + q;
            float* op = opb + row * DH;
            #pragma unroll
            for (int dt = 0; dt < 8; ++dt) {
                float4 v;
                v.x = o[n][dt][0]; v.y = o[n][dt][1]; v.z = o[n][dt][2]; v.w = o[n][dt][3];
                *(float4*)(op + dt * 16 + g * 4) = v;
            }
            if (g == 0) {
                Ml[(size_t)pid * (QT * 2) + row * 2]     = mrun[n];
                Ml[(size_t)pid * (QT * 2) + row * 2 + 1] = lsum[n];
            }
        }
    } else {
        #pragma unroll
        for (int n = 0; n < 2; ++n) {
            const int qrow = qbase + wv * 32 + n * 16 + q;
            if (qrow >= SEQ) continue;
            const float inv = 1.f / (lsum[n] + 64.f * exp2f(-mrun[n]));
            float* op = Og + hoff + (size_t)qrow * DH;
            #pragma unroll
            for (int dt = 0; dt < 8; ++dt) {
                float4 v;
                v.x = o[n][dt][0] * inv; v.y = o[n][dt][1] * inv;
                v.z = o[n][dt][2] * inv; v.w = o[n][dt][3] * inv;
                *(float4*)(op + dt * 16 + g * 4) = v;
            }
        }
    }
    #undef STAGE_V
}

// compile-time-S merge body (runtime-indexed local arrays would go to scratch)
template<int S>
__device__ __forceinline__ void merge_body(const float* __restrict__ Opart,
                                           const float* __restrict__ Ml,
                                           float* __restrict__ Og,
                                           int head, int qbase, int pbase,
                                           int row, int c4) {
    if (qbase + row >= SEQ) return;       // text tail
    float w[S], lv[S];
    float m = -INFINITY;
    #pragma unroll
    for (int s = 0; s < S; ++s) {
        w[s]  = Ml[(size_t)(pbase + s) * (QT * 2) + row * 2];
        lv[s] = Ml[(size_t)(pbase + s) * (QT * 2) + row * 2 + 1];
        m = fmaxf(m, w[s]);
    }
    float L = 64.f * exp2f(-m);           // 64 zero-pad keys (log2 domain)
    #pragma unroll
    for (int s = 0; s < S; ++s) { w[s] = exp2f(w[s] - m); L += w[s] * lv[s]; }
    const float inv = 1.f / L;

    float* op = Og + (size_t)head * SEQ * DH + (size_t)(qbase + row) * DH;
    #pragma unroll
    for (int half = 0; half < 2; ++half) {
        const int j = c4 + half * 16;
        float4 acc = make_float4(0.f, 0.f, 0.f, 0.f);
        #pragma unroll
        for (int s = 0; s < S; ++s) {
            const float4 p = *(const float4*)(Opart + (size_t)(pbase + s) * (QT * DH)
                                              + row * DH + j * 4);
            acc.x += w[s] * p.x; acc.y += w[s] * p.y;
            acc.z += w[s] * p.z; acc.w += w[s] * p.w;
        }
        float4 v; v.x = acc.x * inv; v.y = acc.y * inv; v.z = acc.z * inv; v.w = acc.w * inv;
        *(float4*)(op + j * 4) = v;
    }
}

// 8 blocks per q-tile (16-row slices): 2688 blocks -> not latency-bound
template<int TS, int IS>
__global__ __launch_bounds__(256) void sta_merge(const float* __restrict__ Opart,
                                                 const float* __restrict__ Ml,
                                                 float* __restrict__ Og) {
    const int bb = blockIdx.x;
    const int b = bb >> 3, slice = bb & 7;
    const int t = threadIdx.x;
    const int row = slice * 16 + (t >> 4);   // 0..127
    const int c4  = t & 15;                  // float4 column
    if (b < NHEADS * NTT) {
        merge_body<TS>(Opart, Ml, Og, b / NTT, IMG_LEN + (b % NTT) * QT,
                       b * TS, row, c4);
    } else {
        const int tile = b - NHEADS * NTT;
        merge_body<IS>(Opart, Ml, Og, tile / NIT, (tile % NIT) * QT,
                       NHEADS * NTT * TS + tile * IS, row, c4);
    }
}

extern "C" void kernel_launch(void* const* d_in, const int* in_sizes, int n_in,
                              void* d_out, int out_size, void* d_ws, size_t ws_size,
                              hipStream_t stream) {
    const float* Qg = (const float*)d_in[0];
    const float* Kg = (const float*)d_in[1];
    const float* Vg = (const float*)d_in[2];
    float* Og = (float*)d_out;
    char* wsb = (char*)d_ws;

    unsigned short* Kb  = (unsigned short*)wsb;
    unsigned short* VTb = (unsigned short*)(wsb + KB_BYTES);
    float* Opart = (float*)(wsb + 2 * KB_BYTES);
    const int nprep  = 2672 + NHEADS * 2 * 167;    // 4008
    const int nmerge = NHEADS * (NTT + NIT) * 8;   // 2688

    if (ws_size >= 2 * KB_BYTES + Geo<8, 4>::WS_FLOATS * sizeof(float)) {
        float* Ml = Opart + (size_t)Geo<8, 4>::NPID * QT * DH;
        hipLaunchKernelGGL(sta_prep, dim3(nprep), dim3(256), 0, stream, Kg, Vg, Kb, VTb);
        hipLaunchKernelGGL((sta_attn<8, 4, true>), dim3(Geo<8, 4>::NPID), dim3(256), 0, stream,
                           Qg, Kb, VTb, Og, Opart, Ml);
        hipLaunchKernelGGL((sta_merge<8, 4>), dim3(nmerge), dim3(256), 0, stream,
                           Opart, Ml, Og);
    } else if (ws_size >= 2 * KB_BYTES + Geo<4, 2>::WS_FLOATS * sizeof(float)) {
        float* Ml = Opart + (size_t)Geo<4, 2>::NPID * QT * DH;
        hipLaunchKernelGGL(sta_prep, dim3(nprep), dim3(256), 0, stream, Kg, Vg, Kb, VTb);
        hipLaunchKernelGGL((sta_attn<4, 2, true>), dim3(Geo<4, 2>::NPID), dim3(256), 0, stream,
                           Qg, Kb, VTb, Og, Opart, Ml);
        hipLaunchKernelGGL((sta_merge<4, 2>), dim3(nmerge), dim3(256), 0, stream,
                           Opart, Ml, Og);
    } else {
        // last-resort: unsplit, still pre-pass (needs ~22MB; proven ws >= 93MB)
        hipLaunchKernelGGL(sta_prep, dim3(nprep), dim3(256), 0, stream, Kg, Vg, Kb, VTb);
        hipLaunchKernelGGL((sta_attn<1, 1, false>), dim3(Geo<1, 1>::NPID), dim3(256), 0, stream,
                           Qg, Kb, VTb, Og, (float*)nullptr, (float*)nullptr);
    }
}

// Round 14
// 204.424 us; speedup vs baseline: 1.2288x; 1.2288x over previous
//
#include <hip/hip_runtime.h>

// ---- problem constants (from reference) ----
#define SEQ      10688      // IMG_LEN + TEXT_LEN
#define IMG_LEN  10368      // 18*24*24
#define TEXT_LEN 320
#define DH       128
#define NHEADS   4
#define SLAB     3456       // 6*24*24 tokens per time-slab
#define KVC      32         // kv chunk rows
#define NCHT     334        // SEQ/KVC total chunks
#define QT       128        // q rows per block (4 waves x 32)
#define NIT      81         // image q-tiles per head
#define NTT      3          // text q-tiles per head (last tile half-valid)
#define NCH_TXT  334
#define NCH_IMG  118        // 108 slab chunks + 10 text chunks
#define SCALEL2E 0.12751744518924593f   // (1/sqrt(128)) * log2(e)
#define DEFER_THR 8.0f      // defer-max rescale threshold (T13)

typedef __bf16 bf16x8 __attribute__((ext_vector_type(8)));
typedef __bf16 bf16x4 __attribute__((ext_vector_type(4)));
typedef float  f32x4  __attribute__((ext_vector_type(4)));

__device__ __forceinline__ unsigned pk2bf(float a, float b) {
    union { __bf16 h[2]; unsigned u; } t;
    t.h[0] = (__bf16)a; t.h[1] = (__bf16)b;
    return t.u;
}

__device__ __forceinline__ void gload_lds16(const void* g, void* l) {
    __builtin_amdgcn_global_load_lds(
        (const __attribute__((address_space(1))) void*)g,
        (__attribute__((address_space(3))) void*)l, 16, 0, 0);
}

__device__ __forceinline__ void split_range(int total, int nsplit, int s, int& c0, int& n) {
    const int q = total / nsplit, r = total % nsplit;
    if (s < r) { c0 = s * (q + 1); n = q + 1; }
    else       { c0 = r * (q + 1) + (s - r) * q; n = q; }
}

template<int TS, int IS> struct Geo {
    static constexpr int NTXTB = NHEADS * NTT * TS;
    static constexpr int NIMGB = NHEADS * NIT * IS;
    static constexpr int NPID  = NTXTB + NIMGB;
    static constexpr size_t WS_FLOATS = (size_t)NPID * (QT * DH + QT * 2);
};
#define KB_BYTES ((size_t)NHEADS * SEQ * DH * 2)   // bf16 K (or V-frag) array size

// ---- pre-pass ----
// K -> bf16, same [kv][d] layout.
// V -> bf16 in PV-FRAGMENT order: for chunk c (32 kv), fragment block
// (kt,dh2) is 1KB where lane l's 16B = V[c*32+kt*16+(l>>4)*4 + 0..3]
// [d = (dh2*2+par)*16 + (l&15)] packed as two bf16x4 (par=0 lo, par=1 hi).
// Attn then reads V as 8 coalesced dwordx4/chunk -> NO LDS for V.
__global__ __launch_bounds__(256) void sta_prep(const float* __restrict__ Kg,
                                                const float* __restrict__ Vg,
                                                unsigned short* __restrict__ Kb,
                                                uint4* __restrict__ Vf) {
    __shared__ float T[64][65];
    const int b = blockIdx.x;
    if (b < 2672) {                      // K convert: 4*SEQ*128 elems, 8/thread
        const size_t i = ((size_t)b * 256 + threadIdx.x) * 8;
        float4 a = *(const float4*)(Kg + i);
        float4 c = *(const float4*)(Kg + i + 4);
        uint4 u; u.x = pk2bf(a.x, a.y); u.y = pk2bf(a.z, a.w);
                 u.z = pk2bf(c.x, c.y); u.w = pk2bf(c.z, c.w);
        *(uint4*)(Kb + i) = u;
    } else {                             // V: 64kv x 64d tile -> fragment order
        const int bb = b - 2672;
        const int dhalf = bb & 1, kvt = (bb >> 1) % 167, h = (bb >> 1) / 167;
        const float* src = Vg + ((size_t)h * SEQ + kvt * 64) * DH + dhalf * 64;
        const int t = threadIdx.x;
        const int col = t & 63, r4 = t >> 6;
        #pragma unroll
        for (int i = 0; i < 16; ++i) {
            const int row = i * 4 + r4;
            T[row][col] = src[(size_t)row * DH + col];
        }
        __syncthreads();
        const int lane = t & 63, q = t & 15, gg = lane >> 4;
        #pragma unroll
        for (int i = 0; i < 2; ++i) {
            const int idx = (t >> 6) * 2 + i;      // 0..7: ch2(2) x kt(2) x dtp(2)
            const int ch2 = idx >> 2, kt = (idx >> 1) & 1, dtp = idx & 1;
            const int kvl = ch2 * 32 + kt * 16 + gg * 4;
            const int dle = dtp * 32 + q;          // d-local of even dt
            const int dlo = dle + 16;
            uint4 u;
            u.x = pk2bf(T[kvl][dle],     T[kvl + 1][dle]);
            u.y = pk2bf(T[kvl + 2][dle], T[kvl + 3][dle]);
            u.z = pk2bf(T[kvl][dlo],     T[kvl + 1][dlo]);
            u.w = pk2bf(T[kvl + 2][dlo], T[kvl + 3][dlo]);
            const size_t o4 = ((size_t)(h * 334 + kvt * 2 + ch2) * 8
                               + kt * 4 + dhalf * 2 + dtp) * 64 + lane;
            Vf[o4] = u;
        }
    }
}

// K via LDS-DMA (R11 path, proven). V via coalesced register loads from the
// fragment-ordered array: PV un-swapped, mfma(A=P, B=Vfrag) -> D=O[q][d]
// (row=q-in-group, col=d). DS volume halves (was the measured bound: 16 waves
// x 192cy = 3072cy/slot == 3036 measured). Rescale/inv need per-element
// factors (4 shuffles per event; defer-max makes rescale rare).
// NOTE: NO min-waves clamp (rounds 3/5 spill catastrophe).
template<int TS, int IS, bool SPLIT>
__global__ __launch_bounds__(256) void sta_attn(const float* __restrict__ Qg,
                                                const unsigned short* __restrict__ Kb,
                                                const uint4* __restrict__ Vf,
                                                float* __restrict__ Og,
                                                float* __restrict__ Opart,
                                                float* __restrict__ Ml) {
    using G = Geo<TS, IS>;
    // K: [kv][d] bf16 (32x128), 16B-granule XOR key (kv&7), double-buffered.
    __shared__ __align__(16) unsigned short LK[2][KVC * DH];   // 16 KB

    const int tid  = threadIdx.x;
    const int lane = tid & 63;
    const int wv   = tid >> 6;
    const int q    = lane & 15;       // MFMA col position in S^T (q-tilde)
    const int g    = lane >> 4;       // lane group 0..3
    const int sw16 = (q & 7) << 4;    // K-read swizzle key (bytes)

    // per-lane K DMA source offsets (bytes), inverse-swizzled (chunk-invariant)
    int koff[2];
    #pragma unroll
    for (int j = 0; j < 2; ++j) {
        const int idx = wv * 128 + j * 64 + lane;            // linear 16B granule
        koff[j] = (idx >> 4) * 256 + (((idx & 15) ^ ((idx >> 4) & 7)) << 4);
    }

    int b = blockIdx.x;
    int head, qbase, nch, ch0, kvb0, pid = 0;
    bool isText;
    if (b < G::NTXTB) {                        // text splits first (longest poles)
        int tb = b / TS, s = b % TS;
        head = tb / NTT; qbase = IMG_LEN + (tb % NTT) * QT;
        isText = true; kvb0 = 0;
        split_range(NCH_TXT, TS, s, ch0, nch);
        pid = b;
    } else {
        int bb = b - G::NTXTB; int tile = bb / IS, s = bb % IS;
        head = tile / NIT; qbase = (tile % NIT) * QT;
        isText = false; kvb0 = (qbase / SLAB) * SLAB;
        split_range(NCH_IMG, IS, s, ch0, nch);
        pid = G::NTXTB + bb;
    }

    const size_t hoff = (size_t)head * SEQ * DH;
    const float* Qh = Qg + hoff;
    const char* khb = (const char*)Kb + hoff * 2;             // kv-row stride 256B
    const uint4* vbh = Vf + (size_t)head * 334 * 512 + lane;  // 512 uint4/chunk

    // ---- Q fragments for 2 q-subtiles (B-operand layout), scale folded ----
    bf16x8 qf[2][4];
    #pragma unroll
    for (int n = 0; n < 2; ++n) {
        int qr = qbase + wv * 32 + n * 16 + q;
        if (qr > SEQ - 1) qr = SEQ - 1;        // text tail: clamp (discarded at store)
        const float* qp = Qh + (size_t)qr * DH;
        #pragma unroll
        for (int c = 0; c < 4; ++c) {
            float4 a = *(const float4*)(qp + c * 32 + g * 8);
            float4 d = *(const float4*)(qp + c * 32 + g * 8 + 4);
            union { unsigned u[4]; bf16x8 v; } t;
            t.u[0] = pk2bf(a.x * SCALEL2E, a.y * SCALEL2E);
            t.u[1] = pk2bf(a.z * SCALEL2E, a.w * SCALEL2E);
            t.u[2] = pk2bf(d.x * SCALEL2E, d.y * SCALEL2E);
            t.u[3] = pk2bf(d.z * SCALEL2E, d.w * SCALEL2E);
            qf[n][c] = t.v;
        }
    }

    // o layout (un-swapped PV): o[n][dt][r] = O[q = n*16+g*4+r][d = dt*16+qtilde]
    f32x4 o[2][8];
    #pragma unroll
    for (int n = 0; n < 2; ++n)
        #pragma unroll
        for (int dt = 0; dt < 8; ++dt) o[n][dt] = f32x4{0.f, 0.f, 0.f, 0.f};
    float mrun[2] = {-INFINITY, -INFINITY};   // stats in qtilde-space (lane&15)
    float lsum[2] = {0.f, 0.f};

    auto kvaddr = [&](int gch) -> int {
        return isText ? gch * KVC
                      : (gch < 108 ? kvb0 + gch * KVC : IMG_LEN + (gch - 108) * KVC);
    };

    #define STAGE_K(BUF, KB)                                                     \
        {   const char* ks = khb + (size_t)(KB) * 256;                           \
            gload_lds16(ks + koff[0], &LK[BUF][wv * 1024]);                      \
            gload_lds16(ks + koff[1], &LK[BUF][wv * 1024 + 512]);                \
        }

    STAGE_K(0, kvaddr(ch0));
    if (nch > 1) STAGE_K(1, kvaddr(ch0 + 1));
    __syncthreads();                       // drains K DMA + syncs

    for (int ch = 0; ch < nch; ++ch) {
        const int buf = ch & 1;
        const int kb = kvaddr(ch0 + ch);

        // ---- V fragments for THIS chunk: 8 coalesced dwordx4 (issued first so
        // the pre-PV waitcnt leaves the K DMAs outstanding) ----
        const uint4* vp = vbh + (size_t)(kb >> 5) * 512;
        uint4 vf4[2][4];
        #pragma unroll
        for (int kt = 0; kt < 2; ++kt)
            #pragma unroll
            for (int dh2 = 0; dh2 < 4; ++dh2)
                vf4[kt][dh2] = vp[(kt * 4 + dh2) * 64];

        // K DMA for ch+1 into LK[(ch+1)&1] (last read at ch-1, barrier-protected)
        if (ch > 0 && ch + 1 < nch) STAGE_K(buf ^ 1, kvaddr(ch0 + ch + 1));

        // ---- S^T = K * Q^T : st[n][kt][r] = S[kv=kt*16+g*4+r][q=n*16+qtilde] ----
        f32x4 st[2][2];
        #pragma unroll
        for (int n = 0; n < 2; ++n)
            #pragma unroll
            for (int kt = 0; kt < 2; ++kt) st[n][kt] = f32x4{0.f, 0.f, 0.f, 0.f};
        __builtin_amdgcn_s_setprio(1);
        #pragma unroll
        for (int c = 0; c < 4; ++c) {
            #pragma unroll
            for (int kt = 0; kt < 2; ++kt) {
                bf16x8 kf = *(const bf16x8*)((const char*)&LK[buf][0]
                              + (kt*16 + q) * 256 + ((c * 64 + g * 16) ^ sw16));
                st[0][kt] = __builtin_amdgcn_mfma_f32_16x16x32_bf16(kf, qf[0][c], st[0][kt], 0, 0, 0);
                st[1][kt] = __builtin_amdgcn_mfma_f32_16x16x32_bf16(kf, qf[1][c], st[1][kt], 0, 0, 0);
            }
        }
        __builtin_amdgcn_s_setprio(0);

        // ---- online softmax (log2 domain), defer-max ----
        float cm[2];
        #pragma unroll
        for (int n = 0; n < 2; ++n) {
            float a0 = fmaxf(fmaxf(st[n][0][0], st[n][0][1]), fmaxf(st[n][0][2], st[n][0][3]));
            float a1 = fmaxf(fmaxf(st[n][1][0], st[n][1][1]), fmaxf(st[n][1][2], st[n][1][3]));
            float c0 = fmaxf(a0, a1);
            c0 = fmaxf(c0, __shfl_xor(c0, 16));
            c0 = fmaxf(c0, __shfl_xor(c0, 32));
            cm[n] = c0;
        }
        if (!__all((cm[0] <= mrun[0] + DEFER_THR) && (cm[1] <= mrun[1] + DEFER_THR))) {
            #pragma unroll
            for (int n = 0; n < 2; ++n) {
                float mnew = fmaxf(mrun[n], cm[n]);
                float sc = exp2f(mrun[n] - mnew);
                lsum[n] *= sc;
                mrun[n] = mnew;
                // o rows are q=n*16+g*4+r: fetch sc for those q (4 shuffles)
                f32x4 scv;
                #pragma unroll
                for (int r = 0; r < 4; ++r)
                    scv[r] = __shfl(sc, (lane & 48) + g * 4 + r);
                #pragma unroll
                for (int dt = 0; dt < 8; ++dt) o[n][dt] *= scv;
            }
        }

        // P in bf16: A-operand layout (m=qtilde, k=g*4+r) IS the st layout.
        bf16x4 pkv[2][2];
        #pragma unroll
        for (int n = 0; n < 2; ++n) {
            float ps = 0.f;
            #pragma unroll
            for (int kt = 0; kt < 2; ++kt) {
                float p0 = exp2f(st[n][kt][0] - mrun[n]);
                float p1 = exp2f(st[n][kt][1] - mrun[n]);
                float p2 = exp2f(st[n][kt][2] - mrun[n]);
                float p3 = exp2f(st[n][kt][3] - mrun[n]);
                ps += (p0 + p1) + (p2 + p3);
                union { unsigned u[2]; bf16x4 v; } t;
                t.u[0] = pk2bf(p0, p1);
                t.u[1] = pk2bf(p2, p3);
                pkv[n][kt] = t.v;
            }
            ps += __shfl_xor(ps, 16);
            ps += __shfl_xor(ps, 32);
            lsum[n] += ps;
        }

        // ---- O += P * V : A=pkv regs, B=V frags (registers), no LDS ----
        __builtin_amdgcn_s_setprio(1);
        #pragma unroll
        for (int kt = 0; kt < 2; ++kt) {
            #pragma unroll
            for (int dt = 0; dt < 8; ++dt) {
                bf16x4 vb = ((const bf16x4*)&vf4[kt][dt >> 1])[dt & 1];
                asm("v_mfma_f32_16x16x16_bf16 %0, %1, %2, %0"
                    : "+v"(o[0][dt]) : "v"(pkv[0][kt]), "v"(vb));
                asm("v_mfma_f32_16x16x16_bf16 %0, %1, %2, %0"
                    : "+v"(o[1][dt]) : "v"(pkv[1][kt]), "v"(vb));
            }
        }
        __builtin_amdgcn_s_setprio(0);

        if (ch + 1 < nch) __syncthreads();     // K DMA drain + reader sync
    }

    // hazard insurance: asm MFMA writes o[], epilogue VALU reads it soon after
    asm volatile("s_nop 7\n\ts_nop 7");

    if constexpr (SPLIT) {
        float* opb = Opart + (size_t)pid * (QT * DH);
        #pragma unroll
        for (int n = 0; n < 2; ++n) {
            #pragma unroll
            for (int r = 0; r < 4; ++r) {
                const int row = wv * 32 + n * 16 + g * 4 + r;
                float* op = opb + row * DH + q;
                #pragma unroll
                for (int dt = 0; dt < 8; ++dt) op[dt * 16] = o[n][dt][r];
            }
            if (g == 0) {
                const int srow = wv * 32 + n * 16 + q;
                Ml[(size_t)pid * (QT * 2) + srow * 2]     = mrun[n];
                Ml[(size_t)pid * (QT * 2) + srow * 2 + 1] = lsum[n];
            }
        }
    } else {
        #pragma unroll
        for (int n = 0; n < 2; ++n) {
            const float inv = 1.f / (lsum[n] + 64.f * exp2f(-mrun[n]));
            f32x4 invv;
            #pragma unroll
            for (int r = 0; r < 4; ++r)
                invv[r] = __shfl(inv, (lane & 48) + g * 4 + r);
            #pragma unroll
            for (int r = 0; r < 4; ++r) {
                const int qrow = qbase + wv * 32 + n * 16 + g * 4 + r;
                if (qrow >= SEQ) continue;
                float* op = Og + hoff + (size_t)qrow * DH + q;
                #pragma unroll
                for (int dt = 0; dt < 8; ++dt) op[dt * 16] = o[n][dt][r] * invv[r];
            }
        }
    }
    #undef STAGE_K
}

// compile-time-S merge body (runtime-indexed local arrays would go to scratch)
template<int S>
__device__ __forceinline__ void merge_body(const float* __restrict__ Opart,
                                           const float* __restrict__ Ml,
                                           float* __restrict__ Og,
                                           int head, int qbase, int pbase,
                                           int row, int c4) {
    if (qbase + row >= SEQ) return;       // text tail
    float w[S], lv[S];
    float m = -INFINITY;
    #pragma unroll
    for (int s = 0; s < S; ++s) {
        w[s]  = Ml[(size_t)(pbase + s) * (QT * 2) + row * 2];
        lv[s] = Ml[(size_t)(pbase + s) * (QT * 2) + row * 2 + 1];
        m = fmaxf(m, w[s]);
    }
    float L = 64.f * exp2f(-m);           // 64 zero-pad keys (log2 domain)
    #pragma unroll
    for (int s = 0; s < S; ++s) { w[s] = exp2f(w[s] - m); L += w[s] * lv[s]; }
    const float inv = 1.f / L;

    float* op = Og + (size_t)head * SEQ * DH + (size_t)(qbase + row) * DH;
    #pragma unroll
    for (int half = 0; half < 2; ++half) {
        const int j = c4 + half * 16;
        float4 acc = make_float4(0.f, 0.f, 0.f, 0.f);
        #pragma unroll
        for (int s = 0; s < S; ++s) {
            const float4 p = *(const float4*)(Opart + (size_t)(pbase + s) * (QT * DH)
                                              + row * DH + j * 4);
            acc.x += w[s] * p.x; acc.y += w[s] * p.y;
            acc.z += w[s] * p.z; acc.w += w[s] * p.w;
        }
        float4 v; v.x = acc.x * inv; v.y = acc.y * inv; v.z = acc.z * inv; v.w = acc.w * inv;
        *(float4*)(op + j * 4) = v;
    }
}

// 8 blocks per q-tile (16-row slices): 2688 blocks -> not latency-bound
template<int TS, int IS>
__global__ __launch_bounds__(256) void sta_merge(const float* __restrict__ Opart,
                                                 const float* __restrict__ Ml,
                                                 float* __restrict__ Og) {
    const int bb = blockIdx.x;
    const int b = bb >> 3, slice = bb & 7;
    const int t = threadIdx.x;
    const int row = slice * 16 + (t >> 4);   // 0..127
    const int c4  = t & 15;                  // float4 column
    if (b < NHEADS * NTT) {
        merge_body<TS>(Opart, Ml, Og, b / NTT, IMG_LEN + (b % NTT) * QT,
                       b * TS, row, c4);
    } else {
        const int tile = b - NHEADS * NTT;
        merge_body<IS>(Opart, Ml, Og, tile / NIT, (tile % NIT) * QT,
                       NHEADS * NTT * TS + tile * IS, row, c4);
    }
}

extern "C" void kernel_launch(void* const* d_in, const int* in_sizes, int n_in,
                              void* d_out, int out_size, void* d_ws, size_t ws_size,
                              hipStream_t stream) {
    const float* Qg = (const float*)d_in[0];
    const float* Kg = (const float*)d_in[1];
    const float* Vg = (const float*)d_in[2];
    float* Og = (float*)d_out;
    char* wsb = (char*)d_ws;

    unsigned short* Kb = (unsigned short*)wsb;
    uint4* Vfb = (uint4*)(wsb + KB_BYTES);
    float* Opart = (float*)(wsb + 2 * KB_BYTES);
    const int nprep  = 2672 + NHEADS * 2 * 167;    // 4008
    const int nmerge = NHEADS * (NTT + NIT) * 8;   // 2688

    if (ws_size >= 2 * KB_BYTES + Geo<8, 4>::WS_FLOATS * sizeof(float)) {
        float* Ml = Opart + (size_t)Geo<8, 4>::NPID * QT * DH;
        hipLaunchKernelGGL(sta_prep, dim3(nprep), dim3(256), 0, stream, Kg, Vg, Kb, Vfb);
        hipLaunchKernelGGL((sta_attn<8, 4, true>), dim3(Geo<8, 4>::NPID), dim3(256), 0, stream,
                           Qg, Kb, Vfb, Og, Opart, Ml);
        hipLaunchKernelGGL((sta_merge<8, 4>), dim3(nmerge), dim3(256), 0, stream,
                           Opart, Ml, Og);
    } else if (ws_size >= 2 * KB_BYTES + Geo<4, 2>::WS_FLOATS * sizeof(float)) {
        float* Ml = Opart + (size_t)Geo<4, 2>::NPID * QT * DH;
        hipLaunchKernelGGL(sta_prep, dim3(nprep), dim3(256), 0, stream, Kg, Vg, Kb, Vfb);
        hipLaunchKernelGGL((sta_attn<4, 2, true>), dim3(Geo<4, 2>::NPID), dim3(256), 0, stream,
                           Qg, Kb, Vfb, Og, Opart, Ml);
        hipLaunchKernelGGL((sta_merge<4, 2>), dim3(nmerge), dim3(256), 0, stream,
                           Opart, Ml, Og);
    } else {
        // last-resort: unsplit, still pre-pass (needs ~22MB; proven ws >= 93MB)
        hipLaunchKernelGGL(sta_prep, dim3(nprep), dim3(256), 0, stream, Kg, Vg, Kb, Vfb);
        hipLaunchKernelGGL((sta_attn<1, 1, false>), dim3(Geo<1, 1>::NPID), dim3(256), 0, stream,
                           Qg, Kb, Vfb, Og, (float*)nullptr, (float*)nullptr);
    }
}

// Round 16
// 197.455 us; speedup vs baseline: 1.2722x; 1.0353x over previous
//
#include <hip/hip_runtime.h>

// ---- problem constants (from reference) ----
#define SEQ      10688      // IMG_LEN + TEXT_LEN
#define IMG_LEN  10368      // 18*24*24
#define TEXT_LEN 320
#define DH       128
#define NHEADS   4
#define SLAB     3456       // 6*24*24 tokens per time-slab
#define KVC      32         // kv chunk rows
#define QT       128        // q rows per block (4 waves x 32)
#define NIT      81         // image q-tiles per head
#define NTT      3          // text q-tiles per head (last tile half-valid)
#define NCH_TXT  334
#define NCH_IMG  118        // 108 slab chunks + 10 text chunks
#define SCALEL2E 0.12751744518924593f   // (1/sqrt(128)) * log2(e)
#define DEFER_THR 8.0f      // defer-max rescale threshold (T13)

typedef __bf16 bf16x8 __attribute__((ext_vector_type(8)));
typedef __bf16 bf16x4 __attribute__((ext_vector_type(4)));
typedef float  f32x4  __attribute__((ext_vector_type(4)));

__device__ __forceinline__ unsigned pk2bf(float a, float b) {
    union { __bf16 h[2]; unsigned u; } t;
    t.h[0] = (__bf16)a; t.h[1] = (__bf16)b;
    return t.u;
}

__device__ __forceinline__ void gload_lds16(const void* g, void* l) {
    __builtin_amdgcn_global_load_lds(
        (const __attribute__((address_space(1))) void*)g,
        (__attribute__((address_space(3))) void*)l, 16, 0, 0);
}

__device__ __forceinline__ void split_range(int total, int nsplit, int s, int& c0, int& n) {
    const int q = total / nsplit, r = total % nsplit;
    if (s < r) { c0 = s * (q + 1); n = q + 1; }
    else       { c0 = r * (q + 1) + (s - r) * q; n = q; }
}

template<int TS, int IS> struct Geo {
    static constexpr int NTXTB = NHEADS * NTT * TS;
    static constexpr int NIMGB = NHEADS * NIT * IS;
    static constexpr int NPID  = NTXTB + NIMGB;
    static constexpr size_t WS_FLOATS = (size_t)NPID * (QT * DH + QT * 2);
};
#define KB_BYTES ((size_t)NHEADS * SEQ * DH * 2)   // bf16 K (or V-frag) array size

// ---- pre-pass ----
// K -> bf16, same [kv][d] layout.
// V -> bf16 in PV-FRAGMENT order (see R14): 8 coalesced dwordx4/chunk in attn.
__global__ __launch_bounds__(256) void sta_prep(const float* __restrict__ Kg,
                                                const float* __restrict__ Vg,
                                                unsigned short* __restrict__ Kb,
                                                uint4* __restrict__ Vf) {
    __shared__ float T[64][65];
    const int b = blockIdx.x;
    if (b < 2672) {                      // K convert: 4*SEQ*128 elems, 8/thread
        const size_t i = ((size_t)b * 256 + threadIdx.x) * 8;
        float4 a = *(const float4*)(Kg + i);
        float4 c = *(const float4*)(Kg + i + 4);
        uint4 u; u.x = pk2bf(a.x, a.y); u.y = pk2bf(a.z, a.w);
                 u.z = pk2bf(c.x, c.y); u.w = pk2bf(c.z, c.w);
        *(uint4*)(Kb + i) = u;
    } else {                             // V: 64kv x 64d tile -> fragment order
        const int bb = b - 2672;
        const int dhalf = bb & 1, kvt = (bb >> 1) % 167, h = (bb >> 1) / 167;
        const float* src = Vg + ((size_t)h * SEQ + kvt * 64) * DH + dhalf * 64;
        const int t = threadIdx.x;
        const int col = t & 63, r4 = t >> 6;
        #pragma unroll
        for (int i = 0; i < 16; ++i) {
            const int row = i * 4 + r4;
            T[row][col] = src[(size_t)row * DH + col];
        }
        __syncthreads();
        const int lane = t & 63, q = t & 15, gg = lane >> 4;
        #pragma unroll
        for (int i = 0; i < 2; ++i) {
            const int idx = (t >> 6) * 2 + i;      // 0..7: ch2(2) x kt(2) x dtp(2)
            const int ch2 = idx >> 2, kt = (idx >> 1) & 1, dtp = idx & 1;
            const int kvl = ch2 * 32 + kt * 16 + gg * 4;
            const int dle = dtp * 32 + q;          // d-local of even dt
            const int dlo = dle + 16;
            uint4 u;
            u.x = pk2bf(T[kvl][dle],     T[kvl + 1][dle]);
            u.y = pk2bf(T[kvl + 2][dle], T[kvl + 3][dle]);
            u.z = pk2bf(T[kvl][dlo],     T[kvl + 1][dlo]);
            u.w = pk2bf(T[kvl + 2][dlo], T[kvl + 3][dlo]);
            const size_t o4 = ((size_t)(h * 334 + kvt * 2 + ch2) * 8
                               + kt * 4 + dhalf * 2 + dtp) * 64 + lane;
            Vf[o4] = u;
        }
    }
}

// R14 structure (proven 204us) + DEFERRED lsum reduction: lsum[n] is a
// per-lane PARTIAL (this lane's 8 kv slots, row = qtilde), rescaled by the
// group-replicated sc on defer events; the cross-group butterfly (xor 16,32)
// runs ONCE in the epilogue instead of twice per chunk -- removes 4 serial
// ~60cy DS-shuffles per wave-chunk from the softmax critical path.
// Algebraically identical to R14 (all groups share the same mrun reference).
// NOTE: R15's ones-column-lsum MFMA produced NaN (suspect inline-asm C/D quad
// alignment under +10 VGPR pressure) -- reverted, do not re-apply blindly.
// NOTE: NO min-waves clamp (rounds 3/5 spill catastrophe).
template<int TS, int IS, bool SPLIT>
__global__ __launch_bounds__(256) void sta_attn(const float* __restrict__ Qg,
                                                const unsigned short* __restrict__ Kb,
                                                const uint4* __restrict__ Vf,
                                                float* __restrict__ Og,
                                                float* __restrict__ Opart,
                                                float* __restrict__ Ml) {
    using G = Geo<TS, IS>;
    // K: [kv][d] bf16 (32x128), 16B-granule XOR key (kv&7), double-buffered.
    __shared__ __align__(16) unsigned short LK[2][KVC * DH];   // 16 KB

    const int tid  = threadIdx.x;
    const int lane = tid & 63;
    const int wv   = tid >> 6;
    const int q    = lane & 15;       // MFMA col position in S^T (q-tilde)
    const int g    = lane >> 4;       // lane group 0..3
    const int sw16 = (q & 7) << 4;    // K-read swizzle key (bytes)

    // per-lane K DMA source offsets (bytes), inverse-swizzled (chunk-invariant)
    int koff[2];
    #pragma unroll
    for (int j = 0; j < 2; ++j) {
        const int idx = wv * 128 + j * 64 + lane;            // linear 16B granule
        koff[j] = (idx >> 4) * 256 + (((idx & 15) ^ ((idx >> 4) & 7)) << 4);
    }

    int b = blockIdx.x;
    int head, qbase, nch, ch0, kvb0, pid = 0;
    bool isText;
    if (b < G::NTXTB) {                        // text splits first (longest poles)
        int tb = b / TS, s = b % TS;
        head = tb / NTT; qbase = IMG_LEN + (tb % NTT) * QT;
        isText = true; kvb0 = 0;
        split_range(NCH_TXT, TS, s, ch0, nch);
        pid = b;
    } else {
        int bb = b - G::NTXTB; int tile = bb / IS, s = bb % IS;
        head = tile / NIT; qbase = (tile % NIT) * QT;
        isText = false; kvb0 = (qbase / SLAB) * SLAB;
        split_range(NCH_IMG, IS, s, ch0, nch);
        pid = G::NTXTB + bb;
    }

    const size_t hoff = (size_t)head * SEQ * DH;
    const float* Qh = Qg + hoff;
    const char* khb = (const char*)Kb + hoff * 2;             // kv-row stride 256B
    const uint4* vbh = Vf + (size_t)head * 334 * 512 + lane;  // 512 uint4/chunk

    // ---- Q fragments for 2 q-subtiles (B-operand layout), scale folded ----
    bf16x8 qf[2][4];
    #pragma unroll
    for (int n = 0; n < 2; ++n) {
        int qr = qbase + wv * 32 + n * 16 + q;
        if (qr > SEQ - 1) qr = SEQ - 1;        // text tail: clamp (discarded at store)
        const float* qp = Qh + (size_t)qr * DH;
        #pragma unroll
        for (int c = 0; c < 4; ++c) {
            float4 a = *(const float4*)(qp + c * 32 + g * 8);
            float4 d = *(const float4*)(qp + c * 32 + g * 8 + 4);
            union { unsigned u[4]; bf16x8 v; } t;
            t.u[0] = pk2bf(a.x * SCALEL2E, a.y * SCALEL2E);
            t.u[1] = pk2bf(a.z * SCALEL2E, a.w * SCALEL2E);
            t.u[2] = pk2bf(d.x * SCALEL2E, d.y * SCALEL2E);
            t.u[3] = pk2bf(d.z * SCALEL2E, d.w * SCALEL2E);
            qf[n][c] = t.v;
        }
    }

    // o layout (un-swapped PV): o[n][dt][r] = O[q = n*16+g*4+r][d = dt*16+qtilde]
    f32x4 o[2][8];
    #pragma unroll
    for (int n = 0; n < 2; ++n)
        #pragma unroll
        for (int dt = 0; dt < 8; ++dt) o[n][dt] = f32x4{0.f, 0.f, 0.f, 0.f};
    float mrun[2] = {-INFINITY, -INFINITY};    // stats in qtilde-space (lane&15)
    float lsum[2] = {0.f, 0.f};                // PER-LANE partial (deferred reduce)

    auto kvaddr = [&](int gch) -> int {
        return isText ? gch * KVC
                      : (gch < 108 ? kvb0 + gch * KVC : IMG_LEN + (gch - 108) * KVC);
    };

    #define STAGE_K(BUF, KB)                                                     \
        {   const char* ks = khb + (size_t)(KB) * 256;                           \
            gload_lds16(ks + koff[0], &LK[BUF][wv * 1024]);                      \
            gload_lds16(ks + koff[1], &LK[BUF][wv * 1024 + 512]);                \
        }

    STAGE_K(0, kvaddr(ch0));
    if (nch > 1) STAGE_K(1, kvaddr(ch0 + 1));
    __syncthreads();                       // drains K DMA + syncs

    for (int ch = 0; ch < nch; ++ch) {
        const int buf = ch & 1;
        const int kb = kvaddr(ch0 + ch);

        // ---- V fragments for THIS chunk: 8 coalesced dwordx4 (oldest in queue;
        // pre-PV waitcnt leaves the younger K DMAs outstanding) ----
        const uint4* vp = vbh + (size_t)(kb >> 5) * 512;
        uint4 vf4[2][4];
        #pragma unroll
        for (int kt = 0; kt < 2; ++kt)
            #pragma unroll
            for (int dh2 = 0; dh2 < 4; ++dh2)
                vf4[kt][dh2] = vp[(kt * 4 + dh2) * 64];

        // K DMA for ch+1 into LK[(ch+1)&1] (last read at ch-1, barrier-protected)
        if (ch > 0 && ch + 1 < nch) STAGE_K(buf ^ 1, kvaddr(ch0 + ch + 1));

        // ---- S^T = K * Q^T : st[n][kt][r] = S[kv=kt*16+g*4+r][q=n*16+qtilde] ----
        f32x4 st[2][2];
        #pragma unroll
        for (int n = 0; n < 2; ++n)
            #pragma unroll
            for (int kt = 0; kt < 2; ++kt) st[n][kt] = f32x4{0.f, 0.f, 0.f, 0.f};
        __builtin_amdgcn_s_setprio(1);
        #pragma unroll
        for (int c = 0; c < 4; ++c) {
            #pragma unroll
            for (int kt = 0; kt < 2; ++kt) {
                bf16x8 kf = *(const bf16x8*)((const char*)&LK[buf][0]
                              + (kt*16 + q) * 256 + ((c * 64 + g * 16) ^ sw16));
                st[0][kt] = __builtin_amdgcn_mfma_f32_16x16x32_bf16(kf, qf[0][c], st[0][kt], 0, 0, 0);
                st[1][kt] = __builtin_amdgcn_mfma_f32_16x16x32_bf16(kf, qf[1][c], st[1][kt], 0, 0, 0);
            }
        }
        __builtin_amdgcn_s_setprio(0);

        // ---- online softmax (log2 domain), defer-max ----
        float cm[2];
        #pragma unroll
        for (int n = 0; n < 2; ++n) {
            float a0 = fmaxf(fmaxf(st[n][0][0], st[n][0][1]), fmaxf(st[n][0][2], st[n][0][3]));
            float a1 = fmaxf(fmaxf(st[n][1][0], st[n][1][1]), fmaxf(st[n][1][2], st[n][1][3]));
            float c0 = fmaxf(a0, a1);
            c0 = fmaxf(c0, __shfl_xor(c0, 16));
            c0 = fmaxf(c0, __shfl_xor(c0, 32));
            cm[n] = c0;
        }
        if (!__all((cm[0] <= mrun[0] + DEFER_THR) && (cm[1] <= mrun[1] + DEFER_THR))) {
            #pragma unroll
            for (int n = 0; n < 2; ++n) {
                float mnew = fmaxf(mrun[n], cm[n]);
                float sc = exp2f(mrun[n] - mnew);
                lsum[n] *= sc;                 // per-lane partial: same sc, rows match
                mrun[n] = mnew;
                // o rows are q=n*16+g*4+r: fetch sc for those q (4 shuffles, rare)
                f32x4 scv;
                #pragma unroll
                for (int r = 0; r < 4; ++r)
                    scv[r] = __shfl(sc, (lane & 48) + g * 4 + r);
                #pragma unroll
                for (int dt = 0; dt < 8; ++dt) o[n][dt] *= scv;
            }
        }

        // P in bf16: A-operand layout (m=qtilde, k=g*4+r) IS the st layout.
        // lsum accumulates per-lane only (no per-chunk cross-group shuffles).
        bf16x4 pkv[2][2];
        #pragma unroll
        for (int n = 0; n < 2; ++n) {
            float ps = 0.f;
            #pragma unroll
            for (int kt = 0; kt < 2; ++kt) {
                float p0 = exp2f(st[n][kt][0] - mrun[n]);
                float p1 = exp2f(st[n][kt][1] - mrun[n]);
                float p2 = exp2f(st[n][kt][2] - mrun[n]);
                float p3 = exp2f(st[n][kt][3] - mrun[n]);
                ps += (p0 + p1) + (p2 + p3);
                union { unsigned u[2]; bf16x4 v; } t;
                t.u[0] = pk2bf(p0, p1);
                t.u[1] = pk2bf(p2, p3);
                pkv[n][kt] = t.v;
            }
            lsum[n] += ps;
        }

        // ---- O += P * V : A=pkv regs, B=V frags (registers), no LDS ----
        __builtin_amdgcn_s_setprio(1);
        #pragma unroll
        for (int kt = 0; kt < 2; ++kt) {
            #pragma unroll
            for (int dt = 0; dt < 8; ++dt) {
                bf16x4 vb = ((const bf16x4*)&vf4[kt][dt >> 1])[dt & 1];
                asm("v_mfma_f32_16x16x16_bf16 %0, %1, %2, %0"
                    : "+v"(o[0][dt]) : "v"(pkv[0][kt]), "v"(vb));
                asm("v_mfma_f32_16x16x16_bf16 %0, %1, %2, %0"
                    : "+v"(o[1][dt]) : "v"(pkv[1][kt]), "v"(vb));
            }
        }
        __builtin_amdgcn_s_setprio(0);

        if (ch + 1 < nch) __syncthreads();     // K DMA drain + reader sync
    }

    // hazard insurance: asm MFMA writes o[], epilogue VALU reads it soon after
    asm volatile("s_nop 7\n\ts_nop 7");

    // deferred lsum reduction: butterfly across the 4 groups (same qtilde row)
    #pragma unroll
    for (int n = 0; n < 2; ++n) {
        lsum[n] += __shfl_xor(lsum[n], 16);
        lsum[n] += __shfl_xor(lsum[n], 32);
    }

    if constexpr (SPLIT) {
        float* opb = Opart + (size_t)pid * (QT * DH);
        #pragma unroll
        for (int n = 0; n < 2; ++n) {
            #pragma unroll
            for (int r = 0; r < 4; ++r) {
                const int row = wv * 32 + n * 16 + g * 4 + r;
                float* op = opb + row * DH + q;
                #pragma unroll
                for (int dt = 0; dt < 8; ++dt) op[dt * 16] = o[n][dt][r];
            }
            if (g == 0) {
                const int srow = wv * 32 + n * 16 + q;
                Ml[(size_t)pid * (QT * 2) + srow * 2]     = mrun[n];
                Ml[(size_t)pid * (QT * 2) + srow * 2 + 1] = lsum[n];
            }
        }
    } else {
        #pragma unroll
        for (int n = 0; n < 2; ++n) {
            const float inv = 1.f / (lsum[n] + 64.f * exp2f(-mrun[n]));
            f32x4 invv;
            #pragma unroll
            for (int r = 0; r < 4; ++r)
                invv[r] = __shfl(inv, (lane & 48) + g * 4 + r);
            #pragma unroll
            for (int r = 0; r < 4; ++r) {
                const int qrow = qbase + wv * 32 + n * 16 + g * 4 + r;
                if (qrow >= SEQ) continue;
                float* op = Og + hoff + (size_t)qrow * DH + q;
                #pragma unroll
                for (int dt = 0; dt < 8; ++dt) op[dt * 16] = o[n][dt][r] * invv[r];
            }
        }
    }
    #undef STAGE_K
}

// compile-time-S merge body (runtime-indexed local arrays would go to scratch)
template<int S>
__device__ __forceinline__ void merge_body(const float* __restrict__ Opart,
                                           const float* __restrict__ Ml,
                                           float* __restrict__ Og,
                                           int head, int qbase, int pbase,
                                           int row, int c4) {
    if (qbase + row >= SEQ) return;       // text tail
    float w[S], lv[S];
    float m = -INFINITY;
    #pragma unroll
    for (int s = 0; s < S; ++s) {
        w[s]  = Ml[(size_t)(pbase + s) * (QT * 2) + row * 2];
        lv[s] = Ml[(size_t)(pbase + s) * (QT * 2) + row * 2 + 1];
        m = fmaxf(m, w[s]);
    }
    float L = 64.f * exp2f(-m);           // 64 zero-pad keys (log2 domain)
    #pragma unroll
    for (int s = 0; s < S; ++s) { w[s] = exp2f(w[s] - m); L += w[s] * lv[s]; }
    const float inv = 1.f / L;

    float* op = Og + (size_t)head * SEQ * DH + (size_t)(qbase + row) * DH;
    #pragma unroll
    for (int half = 0; half < 2; ++half) {
        const int j = c4 + half * 16;
        float4 acc = make_float4(0.f, 0.f, 0.f, 0.f);
        #pragma unroll
        for (int s = 0; s < S; ++s) {
            const float4 p = *(const float4*)(Opart + (size_t)(pbase + s) * (QT * DH)
                                              + row * DH + j * 4);
            acc.x += w[s] * p.x; acc.y += w[s] * p.y;
            acc.z += w[s] * p.z; acc.w += w[s] * p.w;
        }
        float4 v; v.x = acc.x * inv; v.y = acc.y * inv; v.z = acc.z * inv; v.w = acc.w * inv;
        *(float4*)(op + j * 4) = v;
    }
}

// 8 blocks per q-tile (16-row slices): 2688 blocks -> not latency-bound
template<int TS, int IS>
__global__ __launch_bounds__(256) void sta_merge(const float* __restrict__ Opart,
                                                 const float* __restrict__ Ml,
                                                 float* __restrict__ Og) {
    const int bb = blockIdx.x;
    const int b = bb >> 3, slice = bb & 7;
    const int t = threadIdx.x;
    const int row = slice * 16 + (t >> 4);   // 0..127
    const int c4  = t & 15;                  // float4 column
    if (b < NHEADS * NTT) {
        merge_body<TS>(Opart, Ml, Og, b / NTT, IMG_LEN + (b % NTT) * QT,
                       b * TS, row, c4);
    } else {
        const int tile = b - NHEADS * NTT;
        merge_body<IS>(Opart, Ml, Og, tile / NIT, (tile % NIT) * QT,
                       NHEADS * NTT * TS + tile * IS, row, c4);
    }
}

extern "C" void kernel_launch(void* const* d_in, const int* in_sizes, int n_in,
                              void* d_out, int out_size, void* d_ws, size_t ws_size,
                              hipStream_t stream) {
    const float* Qg = (const float*)d_in[0];
    const float* Kg = (const float*)d_in[1];
    const float* Vg = (const float*)d_in[2];
    float* Og = (float*)d_out;
    char* wsb = (char*)d_ws;

    unsigned short* Kb = (unsigned short*)wsb;
    uint4* Vfb = (uint4*)(wsb + KB_BYTES);
    float* Opart = (float*)(wsb + 2 * KB_BYTES);
    const int nprep  = 2672 + NHEADS * 2 * 167;    // 4008
    const int nmerge = NHEADS * (NTT + NIT) * 8;   // 2688

    if (ws_size >= 2 * KB_BYTES + Geo<8, 4>::WS_FLOATS * sizeof(float)) {
        float* Ml = Opart + (size_t)Geo<8, 4>::NPID * QT * DH;
        hipLaunchKernelGGL(sta_prep, dim3(nprep), dim3(256), 0, stream, Kg, Vg, Kb, Vfb);
        hipLaunchKernelGGL((sta_attn<8, 4, true>), dim3(Geo<8, 4>::NPID), dim3(256), 0, stream,
                           Qg, Kb, Vfb, Og, Opart, Ml);
        hipLaunchKernelGGL((sta_merge<8, 4>), dim3(nmerge), dim3(256), 0, stream,
                           Opart, Ml, Og);
    } else if (ws_size >= 2 * KB_BYTES + Geo<4, 2>::WS_FLOATS * sizeof(float)) {
        float* Ml = Opart + (size_t)Geo<4, 2>::NPID * QT * DH;
        hipLaunchKernelGGL(sta_prep, dim3(nprep), dim3(256), 0, stream, Kg, Vg, Kb, Vfb);
        hipLaunchKernelGGL((sta_attn<4, 2, true>), dim3(Geo<4, 2>::NPID), dim3(256), 0, stream,
                           Qg, Kb, Vfb, Og, Opart, Ml);
        hipLaunchKernelGGL((sta_merge<4, 2>), dim3(nmerge), dim3(256), 0, stream,
                           Opart, Ml, Og);
    } else {
        // last-resort: unsplit, still pre-pass (needs ~22MB; proven ws >= 93MB)
        hipLaunchKernelGGL(sta_prep, dim3(nprep), dim3(256), 0, stream, Kg, Vg, Kb, Vfb);
        hipLaunchKernelGGL((sta_attn<1, 1, false>), dim3(Geo<1, 1>::NPID), dim3(256), 0, stream,
                           Qg, Kb, Vfb, Og, (float*)nullptr, (float*)nullptr);
    }
}

// Round 17
// 172.873 us; speedup vs baseline: 1.4531x; 1.1422x over previous
//
#include <hip/hip_runtime.h>

// ---- problem constants (from reference) ----
#define SEQ      10688      // IMG_LEN + TEXT_LEN
#define IMG_LEN  10368      // 18*24*24
#define TEXT_LEN 320
#define DH       128
#define NHEADS   4
#define SLAB     3456       // 6*24*24 tokens per time-slab
#define KVC      32         // kv chunk rows
#define QT       128        // q rows per block (4 waves x 32)
#define NIT      81         // image q-tiles per head
#define NTT      3          // text q-tiles per head (last tile half-valid)
#define NCH_TXT  334
#define NCH_IMG  118        // 108 slab chunks + 10 text chunks
#define SCALEL2E 0.12751744518924593f   // (1/sqrt(128)) * log2(e)
#define DEFER_THR 8.0f      // defer-max rescale threshold (T13)

typedef __bf16 bf16x8 __attribute__((ext_vector_type(8)));
typedef __bf16 bf16x4 __attribute__((ext_vector_type(4)));
typedef float  f32x4  __attribute__((ext_vector_type(4)));

__device__ __forceinline__ unsigned pk2bf(float a, float b) {
    union { __bf16 h[2]; unsigned u; } t;
    t.h[0] = (__bf16)a; t.h[1] = (__bf16)b;
    return t.u;
}

__device__ __forceinline__ bf16x8 as_bf16x8(uint4 u) {
    union { uint4 a; bf16x8 v; } t; t.a = u; return t.v;
}

__device__ __forceinline__ void split_range(int total, int nsplit, int s, int& c0, int& n) {
    const int q = total / nsplit, r = total % nsplit;
    if (s < r) { c0 = s * (q + 1); n = q + 1; }
    else       { c0 = r * (q + 1) + (s - r) * q; n = q; }
}

template<int TS, int IS> struct Geo {
    static constexpr int NTXTB = NHEADS * NTT * TS;
    static constexpr int NIMGB = NHEADS * NIT * IS;
    static constexpr int NPID  = NTXTB + NIMGB;
    static constexpr size_t WS_FLOATS = (size_t)NPID * (QT * DH + QT * 2);
};
#define KB_BYTES ((size_t)NHEADS * SEQ * DH * 2)   // bf16 K-frag (or V-frag) array

// ---- pre-pass: BOTH K and V to MFMA-fragment order ----
// K frag (chunk of 32 kv, 8 x 1KB blocks, frag = c*2+kt):
//   lane l's 16B = K[ch*32 + kt*16 + (l&15)][c*32 + (l>>4)*8 .. +8]  (bf16x8)
// V frag (see R14): frag = kt*4 + dh2; lane l's 16B = two bf16x4 of
//   V[ch*32+kt*16+(l>>4)*4+0..3][d = (dh2*2+par)*16 + (l&15)].
// Attn reads each as 8 coalesced dwordx4/chunk -> NO LDS, NO barriers.
__global__ __launch_bounds__(256) void sta_prep(const float* __restrict__ Kg,
                                                const float* __restrict__ Vg,
                                                uint4* __restrict__ Kf,
                                                uint4* __restrict__ Vf) {
    __shared__ float T[64][65];
    const int b = blockIdx.x;
    if (b < NHEADS * 334) {              // K-frag: one block per (head, chunk)
        const int hb = b / 334, chunk = b % 334;
        const float* src = Kg + ((size_t)hb * SEQ + chunk * 32) * DH;
        const int t = threadIdx.x;
        #pragma unroll
        for (int i = 0; i < 2; ++i) {
            const int oidx = t + 256 * i;          // 0..511
            const int frag = oidx >> 6, lane = oidx & 63;
            const int c = frag >> 1, kt = frag & 1;
            const int row = kt * 16 + (lane & 15);
            const int col = c * 32 + (lane >> 4) * 8;
            float4 a = *(const float4*)(src + (size_t)row * DH + col);
            float4 d = *(const float4*)(src + (size_t)row * DH + col + 4);
            uint4 u; u.x = pk2bf(a.x, a.y); u.y = pk2bf(a.z, a.w);
                     u.z = pk2bf(d.x, d.y); u.w = pk2bf(d.z, d.w);
            Kf[((size_t)(hb * 334 + chunk) * 8 + frag) * 64 + lane] = u;
        }
    } else {                             // V: 64kv x 64d tile -> fragment order
        const int bb = b - NHEADS * 334;
        const int dhalf = bb & 1, kvt = (bb >> 1) % 167, h = (bb >> 1) / 167;
        const float* src = Vg + ((size_t)h * SEQ + kvt * 64) * DH + dhalf * 64;
        const int t = threadIdx.x;
        const int col = t & 63, r4 = t >> 6;
        #pragma unroll
        for (int i = 0; i < 16; ++i) {
            const int row = i * 4 + r4;
            T[row][col] = src[(size_t)row * DH + col];
        }
        __syncthreads();
        const int lane = t & 63, q = t & 15, gg = lane >> 4;
        #pragma unroll
        for (int i = 0; i < 2; ++i) {
            const int idx = (t >> 6) * 2 + i;      // 0..7: ch2(2) x kt(2) x dtp(2)
            const int ch2 = idx >> 2, kt = (idx >> 1) & 1, dtp = idx & 1;
            const int kvl = ch2 * 32 + kt * 16 + gg * 4;
            const int dle = dtp * 32 + q;          // d-local of even dt
            const int dlo = dle + 16;
            uint4 u;
            u.x = pk2bf(T[kvl][dle],     T[kvl + 1][dle]);
            u.y = pk2bf(T[kvl + 2][dle], T[kvl + 3][dle]);
            u.z = pk2bf(T[kvl][dlo],     T[kvl + 1][dlo]);
            u.w = pk2bf(T[kvl + 2][dlo], T[kvl + 3][dlo]);
            const size_t o4 = ((size_t)(h * 334 + kvt * 2 + ch2) * 8
                               + kt * 4 + dhalf * 2 + dtp) * 64 + lane;
            Vf[o4] = u;
        }
    }
}

// BARRIER-FREE attn: K and V both read as coalesced fragment loads (L1-shared
// across the block's 4 waves); zero LDS; waves fully independent. Per-chunk
// pipeline: V(ch) loads at top (hide under QK+softmax ~600cy); K(ch+1)
// prefetched into dead kf4 regs after pack (hide under PV ~400cy). vmcnt
// in-order: PV's wait retires V while K stays outstanding.
// NOTE: NO min-waves clamp (rounds 3/5 spill catastrophe). Watch VGPR/spills.
template<int TS, int IS, bool SPLIT>
__global__ __launch_bounds__(256) void sta_attn(const float* __restrict__ Qg,
                                                const uint4* __restrict__ Kf,
                                                const uint4* __restrict__ Vf,
                                                float* __restrict__ Og,
                                                float* __restrict__ Opart,
                                                float* __restrict__ Ml) {
    using G = Geo<TS, IS>;
    const int tid  = threadIdx.x;
    const int lane = tid & 63;
    const int wv   = tid >> 6;
    const int q    = lane & 15;       // MFMA col position in S^T (q-tilde)
    const int g    = lane >> 4;       // lane group 0..3

    int b = blockIdx.x;
    int head, qbase, nch, ch0, kvb0, pid = 0;
    bool isText;
    if (b < G::NTXTB) {                        // text splits first (longest poles)
        int tb = b / TS, s = b % TS;
        head = tb / NTT; qbase = IMG_LEN + (tb % NTT) * QT;
        isText = true; kvb0 = 0;
        split_range(NCH_TXT, TS, s, ch0, nch);
        pid = b;
    } else {
        int bb = b - G::NTXTB; int tile = bb / IS, s = bb % IS;
        head = tile / NIT; qbase = (tile % NIT) * QT;
        isText = false; kvb0 = (qbase / SLAB) * SLAB;
        split_range(NCH_IMG, IS, s, ch0, nch);
        pid = G::NTXTB + bb;
    }

    const size_t hoff = (size_t)head * SEQ * DH;
    const float* Qh = Qg + hoff;
    const uint4* kfh = Kf + (size_t)head * 334 * 512 + lane;  // 512 uint4/chunk
    const uint4* vfh = Vf + (size_t)head * 334 * 512 + lane;

    // ---- Q fragments for 2 q-subtiles (B-operand layout), scale folded ----
    bf16x8 qf[2][4];
    #pragma unroll
    for (int n = 0; n < 2; ++n) {
        int qr = qbase + wv * 32 + n * 16 + q;
        if (qr > SEQ - 1) qr = SEQ - 1;        // text tail: clamp (discarded at store)
        const float* qp = Qh + (size_t)qr * DH;
        #pragma unroll
        for (int c = 0; c < 4; ++c) {
            float4 a = *(const float4*)(qp + c * 32 + g * 8);
            float4 d = *(const float4*)(qp + c * 32 + g * 8 + 4);
            union { unsigned u[4]; bf16x8 v; } t;
            t.u[0] = pk2bf(a.x * SCALEL2E, a.y * SCALEL2E);
            t.u[1] = pk2bf(a.z * SCALEL2E, a.w * SCALEL2E);
            t.u[2] = pk2bf(d.x * SCALEL2E, d.y * SCALEL2E);
            t.u[3] = pk2bf(d.z * SCALEL2E, d.w * SCALEL2E);
            qf[n][c] = t.v;
        }
    }

    // o layout (un-swapped PV): o[n][dt][r] = O[q = n*16+g*4+r][d = dt*16+qtilde]
    f32x4 o[2][8];
    #pragma unroll
    for (int n = 0; n < 2; ++n)
        #pragma unroll
        for (int dt = 0; dt < 8; ++dt) o[n][dt] = f32x4{0.f, 0.f, 0.f, 0.f};
    float mrun[2] = {-INFINITY, -INFINITY};    // stats in qtilde-space (lane&15)
    float lsum[2] = {0.f, 0.f};                // per-lane partial (deferred reduce)

    auto kvaddr = [&](int gch) -> int {
        return isText ? gch * KVC
                      : (gch < 108 ? kvb0 + gch * KVC : IMG_LEN + (gch - 108) * KVC);
    };

    // prologue: K fragments for chunk 0
    uint4 kf4[8];
    {
        const uint4* kp = kfh + (size_t)(kvaddr(ch0) >> 5) * 512;
        #pragma unroll
        for (int f = 0; f < 8; ++f) kf4[f] = kp[f * 64];
    }

    for (int ch = 0; ch < nch; ++ch) {
        const int kb = kvaddr(ch0 + ch);

        // ---- V fragments for THIS chunk (oldest in vmcnt queue; consumed at PV) ----
        const uint4* vp = vfh + (size_t)(kb >> 5) * 512;
        uint4 vf4[8];
        #pragma unroll
        for (int f = 0; f < 8; ++f) vf4[f] = vp[f * 64];

        // ---- S^T = K * Q^T from kf4 regs (prefetched last iteration) ----
        f32x4 st[2][2];
        #pragma unroll
        for (int n = 0; n < 2; ++n)
            #pragma unroll
            for (int kt = 0; kt < 2; ++kt) st[n][kt] = f32x4{0.f, 0.f, 0.f, 0.f};
        __builtin_amdgcn_s_setprio(1);
        #pragma unroll
        for (int c = 0; c < 4; ++c) {
            #pragma unroll
            for (int kt = 0; kt < 2; ++kt) {
                bf16x8 kf = as_bf16x8(kf4[c * 2 + kt]);
                st[0][kt] = __builtin_amdgcn_mfma_f32_16x16x32_bf16(kf, qf[0][c], st[0][kt], 0, 0, 0);
                st[1][kt] = __builtin_amdgcn_mfma_f32_16x16x32_bf16(kf, qf[1][c], st[1][kt], 0, 0, 0);
            }
        }
        __builtin_amdgcn_s_setprio(0);

        // ---- online softmax (log2 domain), defer-max ----
        float cm[2];
        #pragma unroll
        for (int n = 0; n < 2; ++n) {
            float a0 = fmaxf(fmaxf(st[n][0][0], st[n][0][1]), fmaxf(st[n][0][2], st[n][0][3]));
            float a1 = fmaxf(fmaxf(st[n][1][0], st[n][1][1]), fmaxf(st[n][1][2], st[n][1][3]));
            float c0 = fmaxf(a0, a1);
            c0 = fmaxf(c0, __shfl_xor(c0, 16));
            c0 = fmaxf(c0, __shfl_xor(c0, 32));
            cm[n] = c0;
        }
        if (!__all((cm[0] <= mrun[0] + DEFER_THR) && (cm[1] <= mrun[1] + DEFER_THR))) {
            #pragma unroll
            for (int n = 0; n < 2; ++n) {
                float mnew = fmaxf(mrun[n], cm[n]);
                float sc = exp2f(mrun[n] - mnew);
                lsum[n] *= sc;                 // per-lane partial: same sc, rows match
                mrun[n] = mnew;
                f32x4 scv;
                #pragma unroll
                for (int r = 0; r < 4; ++r)
                    scv[r] = __shfl(sc, (lane & 48) + g * 4 + r);
                #pragma unroll
                for (int dt = 0; dt < 8; ++dt) o[n][dt] *= scv;
            }
        }

        // P in bf16: A-operand layout (m=qtilde, k=g*4+r) IS the st layout.
        bf16x4 pkv[2][2];
        #pragma unroll
        for (int n = 0; n < 2; ++n) {
            float ps = 0.f;
            #pragma unroll
            for (int kt = 0; kt < 2; ++kt) {
                float p0 = exp2f(st[n][kt][0] - mrun[n]);
                float p1 = exp2f(st[n][kt][1] - mrun[n]);
                float p2 = exp2f(st[n][kt][2] - mrun[n]);
                float p3 = exp2f(st[n][kt][3] - mrun[n]);
                ps += (p0 + p1) + (p2 + p3);
                union { unsigned u[2]; bf16x4 v; } t;
                t.u[0] = pk2bf(p0, p1);
                t.u[1] = pk2bf(p2, p3);
                pkv[n][kt] = t.v;
            }
            lsum[n] += ps;
        }

        // ---- prefetch K(ch+1) into the now-dead kf4 regs (flies under PV) ----
        if (ch + 1 < nch) {
            const uint4* kp = kfh + (size_t)(kvaddr(ch0 + ch + 1) >> 5) * 512;
            #pragma unroll
            for (int f = 0; f < 8; ++f) kf4[f] = kp[f * 64];
        }

        // ---- O += P * V : A=pkv regs, B=V frags (registers), no LDS ----
        __builtin_amdgcn_s_setprio(1);
        #pragma unroll
        for (int kt = 0; kt < 2; ++kt) {
            #pragma unroll
            for (int dt = 0; dt < 8; ++dt) {
                bf16x4 vb = ((const bf16x4*)&vf4[kt * 4 + (dt >> 1)])[dt & 1];
                asm("v_mfma_f32_16x16x16_bf16 %0, %1, %2, %0"
                    : "+v"(o[0][dt]) : "v"(pkv[0][kt]), "v"(vb));
                asm("v_mfma_f32_16x16x16_bf16 %0, %1, %2, %0"
                    : "+v"(o[1][dt]) : "v"(pkv[1][kt]), "v"(vb));
            }
        }
        __builtin_amdgcn_s_setprio(0);
    }

    // hazard insurance: asm MFMA writes o[], epilogue VALU reads it soon after
    asm volatile("s_nop 7\n\ts_nop 7");

    // deferred lsum reduction: butterfly across the 4 groups (same qtilde row)
    #pragma unroll
    for (int n = 0; n < 2; ++n) {
        lsum[n] += __shfl_xor(lsum[n], 16);
        lsum[n] += __shfl_xor(lsum[n], 32);
    }

    if constexpr (SPLIT) {
        float* opb = Opart + (size_t)pid * (QT * DH);
        #pragma unroll
        for (int n = 0; n < 2; ++n) {
            #pragma unroll
            for (int r = 0; r < 4; ++r) {
                const int row = wv * 32 + n * 16 + g * 4 + r;
                float* op = opb + row * DH + q;
                #pragma unroll
                for (int dt = 0; dt < 8; ++dt) op[dt * 16] = o[n][dt][r];
            }
            if (g == 0) {
                const int srow = wv * 32 + n * 16 + q;
                Ml[(size_t)pid * (QT * 2) + srow * 2]     = mrun[n];
                Ml[(size_t)pid * (QT * 2) + srow * 2 + 1] = lsum[n];
            }
        }
    } else {
        #pragma unroll
        for (int n = 0; n < 2; ++n) {
            const float inv = 1.f / (lsum[n] + 64.f * exp2f(-mrun[n]));
            f32x4 invv;
            #pragma unroll
            for (int r = 0; r < 4; ++r)
                invv[r] = __shfl(inv, (lane & 48) + g * 4 + r);
            #pragma unroll
            for (int r = 0; r < 4; ++r) {
                const int qrow = qbase + wv * 32 + n * 16 + g * 4 + r;
                if (qrow >= SEQ) continue;
                float* op = Og + hoff + (size_t)qrow * DH + q;
                #pragma unroll
                for (int dt = 0; dt < 8; ++dt) op[dt * 16] = o[n][dt][r] * invv[r];
            }
        }
    }
}

// compile-time-S merge body (runtime-indexed local arrays would go to scratch)
template<int S>
__device__ __forceinline__ void merge_body(const float* __restrict__ Opart,
                                           const float* __restrict__ Ml,
                                           float* __restrict__ Og,
                                           int head, int qbase, int pbase,
                                           int row, int c4) {
    if (qbase + row >= SEQ) return;       // text tail
    float w[S], lv[S];
    float m = -INFINITY;
    #pragma unroll
    for (int s = 0; s < S; ++s) {
        w[s]  = Ml[(size_t)(pbase + s) * (QT * 2) + row * 2];
        lv[s] = Ml[(size_t)(pbase + s) * (QT * 2) + row * 2 + 1];
        m = fmaxf(m, w[s]);
    }
    float L = 64.f * exp2f(-m);           // 64 zero-pad keys (log2 domain)
    #pragma unroll
    for (int s = 0; s < S; ++s) { w[s] = exp2f(w[s] - m); L += w[s] * lv[s]; }
    const float inv = 1.f / L;

    float* op = Og + (size_t)head * SEQ * DH + (size_t)(qbase + row) * DH;
    #pragma unroll
    for (int half = 0; half < 2; ++half) {
        const int j = c4 + half * 16;
        float4 acc = make_float4(0.f, 0.f, 0.f, 0.f);
        #pragma unroll
        for (int s = 0; s < S; ++s) {
            const float4 p = *(const float4*)(Opart + (size_t)(pbase + s) * (QT * DH)
                                              + row * DH + j * 4);
            acc.x += w[s] * p.x; acc.y += w[s] * p.y;
            acc.z += w[s] * p.z; acc.w += w[s] * p.w;
        }
        float4 v; v.x = acc.x * inv; v.y = acc.y * inv; v.z = acc.z * inv; v.w = acc.w * inv;
        *(float4*)(op + j * 4) = v;
    }
}

// 8 blocks per q-tile (16-row slices): 2688 blocks -> not latency-bound
template<int TS, int IS>
__global__ __launch_bounds__(256) void sta_merge(const float* __restrict__ Opart,
                                                 const float* __restrict__ Ml,
                                                 float* __restrict__ Og) {
    const int bb = blockIdx.x;
    const int b = bb >> 3, slice = bb & 7;
    const int t = threadIdx.x;
    const int row = slice * 16 + (t >> 4);   // 0..127
    const int c4  = t & 15;                  // float4 column
    if (b < NHEADS * NTT) {
        merge_body<TS>(Opart, Ml, Og, b / NTT, IMG_LEN + (b % NTT) * QT,
                       b * TS, row, c4);
    } else {
        const int tile = b - NHEADS * NTT;
        merge_body<IS>(Opart, Ml, Og, tile / NIT, (tile % NIT) * QT,
                       NHEADS * NTT * TS + tile * IS, row, c4);
    }
}

extern "C" void kernel_launch(void* const* d_in, const int* in_sizes, int n_in,
                              void* d_out, int out_size, void* d_ws, size_t ws_size,
                              hipStream_t stream) {
    const float* Qg = (const float*)d_in[0];
    const float* Kg = (const float*)d_in[1];
    const float* Vg = (const float*)d_in[2];
    float* Og = (float*)d_out;
    char* wsb = (char*)d_ws;

    uint4* Kfb = (uint4*)wsb;
    uint4* Vfb = (uint4*)(wsb + KB_BYTES);
    float* Opart = (float*)(wsb + 2 * KB_BYTES);
    const int nprep  = NHEADS * 334 + NHEADS * 2 * 167;   // 1336 + 1336 = 2672
    const int nmerge = NHEADS * (NTT + NIT) * 8;          // 2688

    if (ws_size >= 2 * KB_BYTES + Geo<8, 4>::WS_FLOATS * sizeof(float)) {
        float* Ml = Opart + (size_t)Geo<8, 4>::NPID * QT * DH;
        hipLaunchKernelGGL(sta_prep, dim3(nprep), dim3(256), 0, stream, Kg, Vg, Kfb, Vfb);
        hipLaunchKernelGGL((sta_attn<8, 4, true>), dim3(Geo<8, 4>::NPID), dim3(256), 0, stream,
                           Qg, Kfb, Vfb, Og, Opart, Ml);
        hipLaunchKernelGGL((sta_merge<8, 4>), dim3(nmerge), dim3(256), 0, stream,
                           Opart, Ml, Og);
    } else if (ws_size >= 2 * KB_BYTES + Geo<4, 2>::WS_FLOATS * sizeof(float)) {
        float* Ml = Opart + (size_t)Geo<4, 2>::NPID * QT * DH;
        hipLaunchKernelGGL(sta_prep, dim3(nprep), dim3(256), 0, stream, Kg, Vg, Kfb, Vfb);
        hipLaunchKernelGGL((sta_attn<4, 2, true>), dim3(Geo<4, 2>::NPID), dim3(256), 0, stream,
                           Qg, Kfb, Vfb, Og, Opart, Ml);
        hipLaunchKernelGGL((sta_merge<4, 2>), dim3(nmerge), dim3(256), 0, stream,
                           Opart, Ml, Og);
    } else {
        // last-resort: unsplit, still pre-pass (needs ~22MB; proven ws >= 136MB)
        hipLaunchKernelGGL(sta_prep, dim3(nprep), dim3(256), 0, stream, Kg, Vg, Kfb, Vfb);
        hipLaunchKernelGGL((sta_attn<1, 1, false>), dim3(Geo<1, 1>::NPID), dim3(256), 0, stream,
                           Qg, Kfb, Vfb, Og, (float*)nullptr, (float*)nullptr);
    }
}